// Round 6
// baseline (593.135 us; speedup 1.0000x reference)
//
#include <hip/hip_runtime.h>
#include <hip/hip_bf16.h>

#define F_IN 512
#define NC 64      // HID == N_CLS == 64
#define NITER 10
#define BM 256     // MLP tile rows
#define BK 64      // MLP K tile

// ---------------------------------------------------------------------------
// Init per-node halting state; also set rowptr[N] = E.
__global__ __launch_bounds__(256) void init_state_kernel(
    float* __restrict__ steps, float* __restrict__ sumh, int* __restrict__ cont,
    int* __restrict__ rowptr, int N, int E) {
  int i = blockIdx.x * blockDim.x + threadIdx.x;
  if (i < N) { steps[i] = 1.0f; sumh[i] = 0.0f; cont[i] = 1; }
  if (i == 0) rowptr[N] = E;
}

// ---------------------------------------------------------------------------
// Fused tiled MLP: out[r,:] = relu(x[r,:] @ W1 + b1) @ W2 + b2   (all fp32)
// Block: 256 rows x 64 cols, 256 threads, 8x8 outputs per thread
// (16 FMA per ds_read_b128 -- LDS-throughput optimized).
// xT layout: element (k, r) at xT[k*256 + (r ^ (k & 28))]  (<=2-way banks).
__global__ __launch_bounds__(256) void mlp_kernel(
    const float* __restrict__ x, const float* __restrict__ W1,
    const float* __restrict__ b1, const float* __restrict__ W2,
    const float* __restrict__ b2, float* __restrict__ out, int N) {
  __shared__ float xT[BK * BM];    // 64KB swizzled [k][row] x tile / later hT
  __shared__ float ws[BK * NC];    // 16KB W1 k-tile / later W2
  const int tid  = threadIdx.x;
  const int brow = blockIdx.x * BM;
  const int r0 = (tid >> 3) * 8;   // 32 row-groups of 8
  const int c0 = (tid & 7) * 8;    // 8 col-groups of 8

  float acc[8][8];
#pragma unroll
  for (int j = 0; j < 8; ++j) {
    float bv = b1[c0 + j];
#pragma unroll
    for (int i = 0; i < 8; ++i) acc[i][j] = bv;
  }

  for (int kt = 0; kt < F_IN; kt += BK) {
    // stage x tile (256 rows x 64 k), transposed+swizzled into xT
#pragma unroll
    for (int q = 0; q < 16; ++q) {
      int fidx = q * 256 + tid;          // over 4096 float4s
      int row = fidx >> 4, kq = fidx & 15;
      int gr = brow + row; if (gr >= N) gr = N - 1;
      float4 v = *reinterpret_cast<const float4*>(&x[(size_t)gr * F_IN + kt + kq * 4]);
      float vv[4] = {v.x, v.y, v.z, v.w};
#pragma unroll
      for (int j = 0; j < 4; ++j) {
        int kk = kq * 4 + j;
        xT[kk * BM + (row ^ (kk & 28))] = vv[j];
      }
    }
    // stage W1 k-tile (64 x 64), row-major
#pragma unroll
    for (int q = 0; q < 4; ++q) {
      int fidx = q * 256 + tid;          // over 1024 float4s
      int row = fidx >> 4, kq = fidx & 15;
      *reinterpret_cast<float4*>(&ws[row * NC + kq * 4]) =
          *reinterpret_cast<const float4*>(&W1[(size_t)(kt + row) * NC + kq * 4]);
    }
    __syncthreads();
#pragma unroll 4
    for (int k = 0; k < BK; ++k) {
      float4 xa = *reinterpret_cast<const float4*>(&xT[k * BM + (r0 ^ (k & 28))]);
      float4 xb = *reinterpret_cast<const float4*>(&xT[k * BM + ((r0 + 4) ^ (k & 28))]);
      float4 wa = *reinterpret_cast<const float4*>(&ws[k * NC + c0]);
      float4 wb = *reinterpret_cast<const float4*>(&ws[k * NC + c0 + 4]);
      float xr[8] = {xa.x, xa.y, xa.z, xa.w, xb.x, xb.y, xb.z, xb.w};
      float wr[8] = {wa.x, wa.y, wa.z, wa.w, wb.x, wb.y, wb.z, wb.w};
#pragma unroll
      for (int i = 0; i < 8; ++i)
#pragma unroll
        for (int j = 0; j < 8; ++j) acc[i][j] = fmaf(xr[i], wr[j], acc[i][j]);
    }
    __syncthreads();
  }

  // ReLU; write h transposed+swizzled into xT space; stage W2 into ws
#pragma unroll
  for (int i = 0; i < 8; ++i)
#pragma unroll
    for (int j = 0; j < 8; ++j) {
      int kk = c0 + j;
      int r  = r0 + i;
      xT[kk * BM + (r ^ (kk & 28))] = fmaxf(acc[i][j], 0.0f);
    }
#pragma unroll
  for (int q = 0; q < 4; ++q) {
    int fidx = q * 256 + tid;
    int row = fidx >> 4, kq = fidx & 15;
    *reinterpret_cast<float4*>(&ws[row * NC + kq * 4]) =
        *reinterpret_cast<const float4*>(&W2[(size_t)row * NC + kq * 4]);
  }
  float acc2[8][8];
#pragma unroll
  for (int j = 0; j < 8; ++j) {
    float bv = b2[c0 + j];
#pragma unroll
    for (int i = 0; i < 8; ++i) acc2[i][j] = bv;
  }
  __syncthreads();
#pragma unroll 4
  for (int k = 0; k < NC; ++k) {
    float4 xa = *reinterpret_cast<const float4*>(&xT[k * BM + (r0 ^ (k & 28))]);
    float4 xb = *reinterpret_cast<const float4*>(&xT[k * BM + ((r0 + 4) ^ (k & 28))]);
    float4 wa = *reinterpret_cast<const float4*>(&ws[k * NC + c0]);
    float4 wb = *reinterpret_cast<const float4*>(&ws[k * NC + c0 + 4]);
    float xr[8] = {xa.x, xa.y, xa.z, xa.w, xb.x, xb.y, xb.z, xb.w};
    float wr[8] = {wa.x, wa.y, wa.z, wa.w, wb.x, wb.y, wb.z, wb.w};
#pragma unroll
    for (int i = 0; i < 8; ++i)
#pragma unroll
      for (int j = 0; j < 8; ++j) acc2[i][j] = fmaf(xr[i], wr[j], acc2[i][j]);
  }
#pragma unroll
  for (int i = 0; i < 8; ++i) {
    int gr = brow + r0 + i;
    if (gr < N) {
      float4 oa = make_float4(acc2[i][0], acc2[i][1], acc2[i][2], acc2[i][3]);
      float4 ob = make_float4(acc2[i][4], acc2[i][5], acc2[i][6], acc2[i][7]);
      *reinterpret_cast<float4*>(&out[(size_t)gr * NC + c0]) = oa;
      *reinterpret_cast<float4*>(&out[(size_t)gr * NC + c0 + 4]) = ob;
    }
  }
}

// ---------------------------------------------------------------------------
// Degree histograms: deg_i counts sources (for GCN norm), indeg counts
// destinations (for the pull-CSR). Int atomics -> deterministic.
__global__ __launch_bounds__(256) void hist_kernel(
    const int* __restrict__ ei, int* __restrict__ deg_i,
    int* __restrict__ indeg, int E) {
  int e = blockIdx.x * blockDim.x + threadIdx.x;
  if (e < E) {
    atomicAdd(&deg_i[ei[e]], 1);       // row = edge_index[0]
    atomicAdd(&indeg[ei[E + e]], 1);   // col = edge_index[1]
  }
}

// dis[i] = 1/sqrt(deg_i[i] + 1)   (+1 = self loop; deg always >= 1)
__global__ __launch_bounds__(256) void dis_kernel(
    const int* __restrict__ deg_i, float* __restrict__ dis, int N) {
  int i = blockIdx.x * blockDim.x + threadIdx.x;
  if (i < N) dis[i] = 1.0f / sqrtf((float)(deg_i[i] + 1));
}

// ---------------------------------------------------------------------------
// 3-kernel exclusive scan of indeg -> rowptr  (N = 50000, 196 blocks of 256)
__global__ __launch_bounds__(256) void scan_sum_kernel(
    const int* __restrict__ indeg, int* __restrict__ bsum, int N) {
  __shared__ int sm[256];
  int tid = threadIdx.x;
  int i = blockIdx.x * 256 + tid;
  sm[tid] = (i < N) ? indeg[i] : 0;
  __syncthreads();
  for (int s = 128; s > 0; s >>= 1) {
    if (tid < s) sm[tid] += sm[tid + s];
    __syncthreads();
  }
  if (tid == 0) bsum[blockIdx.x] = sm[0];
}

__global__ __launch_bounds__(256) void scan_bsum_kernel(int* __restrict__ bsum, int nb) {
  __shared__ int sm[256];
  int tid = threadIdx.x;
  int v = (tid < nb) ? bsum[tid] : 0;
  sm[tid] = v;
  __syncthreads();
  for (int s = 1; s < 256; s <<= 1) {
    int t = (tid >= s) ? sm[tid - s] : 0;
    __syncthreads();
    sm[tid] += t;
    __syncthreads();
  }
  if (tid < nb) bsum[tid] = sm[tid] - v;  // exclusive
}

__global__ __launch_bounds__(256) void scan_final_kernel(
    const int* __restrict__ indeg, const int* __restrict__ bsum,
    int* __restrict__ rowptr, int N) {
  __shared__ int sm[256];
  int tid = threadIdx.x;
  int i = blockIdx.x * 256 + tid;
  int v = (i < N) ? indeg[i] : 0;
  sm[tid] = v;
  __syncthreads();
  for (int s = 1; s < 256; s <<= 1) {
    int t = (tid >= s) ? sm[tid - s] : 0;
    __syncthreads();
    sm[tid] += t;
    __syncthreads();
  }
  if (i < N) rowptr[i] = bsum[blockIdx.x] + sm[tid] - v;
}

// ---------------------------------------------------------------------------
// Build destination-CSR entries: csr[pos] = {src, norm} packed as int2.
__global__ __launch_bounds__(256) void scatter_kernel(
    const int* __restrict__ ei, const int* __restrict__ rowptr,
    int* __restrict__ cursor, const float* __restrict__ dis,
    int2* __restrict__ csr, int E) {
  int e = blockIdx.x * blockDim.x + threadIdx.x;
  if (e < E) {
    int s = ei[e];
    int c = ei[E + e];
    int pos = rowptr[c] + atomicAdd(&cursor[c], 1);
    csr[pos] = make_int2(s, __float_as_int(dis[s] * dis[c]));
  }
}

// ---------------------------------------------------------------------------
// One adaptive-propagation step, fully fused. One 64-lane wave per node,
// lane = feature. Pull-based gather over incoming edges, no atomics.
// 8 accumulators -> 8 outstanding gathers to cover L2/L3 latency.
__global__ __launch_bounds__(256) void prop_step_kernel(
    const float* __restrict__ prop, float* __restrict__ prop_new,
    const int2* __restrict__ csr, const int* __restrict__ rowptr,
    const float* __restrict__ dis, const float* __restrict__ hw,
    const float* __restrict__ hb, float* __restrict__ steps,
    float* __restrict__ sumh, int* __restrict__ cont,
    float* __restrict__ xacc, int N) {
  int wid = (int)((blockIdx.x * blockDim.x + threadIdx.x) >> 6);
  if (wid >= N) return;
  int lane = threadIdx.x & 63;
  size_t rowoff = (size_t)wid * NC + lane;

  float oldv = prop[rowoff];
  float dc = dis[wid];
  int beg = __builtin_amdgcn_readfirstlane(rowptr[wid]);
  int end = __builtin_amdgcn_readfirstlane(rowptr[wid + 1]);

  // self-loop: norm = dis[c]^2
  float a[8];
  a[0] = dc * dc * oldv;
#pragma unroll
  for (int u = 1; u < 8; ++u) a[u] = 0.0f;
  int i = beg;
  for (; i + 8 <= end; i += 8) {   // 8 outstanding gathers
    int2 e[8];
#pragma unroll
    for (int u = 0; u < 8; ++u) e[u] = csr[i + u];
#pragma unroll
    for (int u = 0; u < 8; ++u)
      a[u] = fmaf(__int_as_float(e[u].y), prop[(size_t)e[u].x * NC + lane], a[u]);
  }
  for (; i < end; ++i) {
    int2 e0 = csr[i];
    a[0] = fmaf(__int_as_float(e0.y), prop[(size_t)e0.x * NC + lane], a[0]);
  }
  float acc = ((a[0] + a[1]) + (a[2] + a[3])) + ((a[4] + a[5]) + (a[6] + a[7]));
  prop_new[rowoff] = acc;

  // hh = sigmoid(prop_new[c,:] . halt_w + halt_b)
  float z = acc * hw[lane];
#pragma unroll
  for (int off = 32; off > 0; off >>= 1) z += __shfl_xor(z, off);
  z += hb[0];
  float hh = 1.0f / (1.0f + expf(-z));

  float st = steps[wid], sh = sumh[wid];
  int ct = cont[wid];
  bool prob = ((sh + hh) < 0.99f) && (ct != 0);
  float pf = prob ? 1.0f : 0.0f;
  st += pf;
  sh += pf * hh;
  bool cond = prob && (st < (float)NITER);
  float pp = cond ? sh : (1.0f - sh);
  float ctf = ct ? 1.0f : 0.0f;
  xacc[rowoff] += (acc * pp + oldv * (1.0f - pp)) * ctf;
  if (lane == 0) { steps[wid] = st; sumh[wid] = sh; cont[wid] = prob ? 1 : 0; }
}

// ---------------------------------------------------------------------------
// out0 = log_softmax(xacc/steps), out1 = steps, out2 = 1 - sum_h
__global__ __launch_bounds__(256) void final_kernel(
    const float* __restrict__ xacc, const float* __restrict__ steps,
    const float* __restrict__ sumh, float* __restrict__ out0,
    float* __restrict__ out1, float* __restrict__ out2, int N) {
  int wid = (int)((blockIdx.x * blockDim.x + threadIdx.x) >> 6);
  if (wid >= N) return;
  int lane = threadIdx.x & 63;
  float st = steps[wid];
  float v = xacc[(size_t)wid * NC + lane] / st;
  float m = v;
#pragma unroll
  for (int off = 32; off > 0; off >>= 1) m = fmaxf(m, __shfl_xor(m, off));
  float e = expf(v - m);
  float s = e;
#pragma unroll
  for (int off = 32; off > 0; off >>= 1) s += __shfl_xor(s, off);
  out0[(size_t)wid * NC + lane] = v - m - logf(s);
  if (lane == 0) { out1[wid] = st; out2[wid] = 1.0f - sumh[wid]; }
}

// ---------------------------------------------------------------------------
extern "C" void kernel_launch(void* const* d_in, const int* in_sizes, int n_in,
                              void* d_out, int out_size, void* d_ws, size_t ws_size,
                              hipStream_t stream) {
  const float* x      = (const float*)d_in[0];
  const int*   ei     = (const int*)d_in[1];
  const float* W1     = (const float*)d_in[2];
  const float* b1     = (const float*)d_in[3];
  const float* W2     = (const float*)d_in[4];
  const float* b2     = (const float*)d_in[5];
  const float* halt_w = (const float*)d_in[6];
  const float* halt_b = (const float*)d_in[7];

  const int N = in_sizes[0] / F_IN;   // 50000
  const int E = in_sizes[1] / 2;      // 800000

  // workspace carve-up (256B aligned)
  char* p = (char*)d_ws;
  auto alloc = [&](size_t bytes) {
    void* r = (void*)p;
    p += (bytes + 255) & ~(size_t)255;
    return r;
  };
  float* propA  = (float*)alloc((size_t)N * NC * 4);
  float* propB  = (float*)alloc((size_t)N * NC * 4);
  float* xacc   = (float*)alloc((size_t)N * NC * 4);
  int2*  csr    = (int2*)alloc((size_t)E * 8);
  int*   rowptr = (int*)alloc((size_t)(N + 1) * 4);
  int*   deg_i  = (int*)alloc((size_t)N * 4);
  int*   indeg  = (int*)alloc((size_t)N * 4);
  int*   cursor = (int*)alloc((size_t)N * 4);
  float* dis    = (float*)alloc((size_t)N * 4);
  float* steps  = (float*)alloc((size_t)N * 4);
  float* sumh   = (float*)alloc((size_t)N * 4);
  int*   cont   = (int*)alloc((size_t)N * 4);
  int*   bsum   = (int*)alloc(1024);

  hipMemsetAsync(deg_i,  0, (size_t)N * 4, stream);
  hipMemsetAsync(indeg,  0, (size_t)N * 4, stream);
  hipMemsetAsync(cursor, 0, (size_t)N * 4, stream);
  hipMemsetAsync(xacc,   0, (size_t)N * NC * 4, stream);

  const int nbN = (N + 255) / 256;   // 196
  const int nbE = (E + 255) / 256;   // 3125
  const int nbM = (N + BM - 1) / BM; // 196

  init_state_kernel<<<nbN, 256, 0, stream>>>(steps, sumh, cont, rowptr, N, E);
  mlp_kernel<<<nbM, 256, 0, stream>>>(x, W1, b1, W2, b2, propA, N);
  hist_kernel<<<nbE, 256, 0, stream>>>(ei, deg_i, indeg, E);
  dis_kernel<<<nbN, 256, 0, stream>>>(deg_i, dis, N);
  scan_sum_kernel<<<nbN, 256, 0, stream>>>(indeg, bsum, N);
  scan_bsum_kernel<<<1, 256, 0, stream>>>(bsum, nbN);
  scan_final_kernel<<<nbN, 256, 0, stream>>>(indeg, bsum, rowptr, N);
  scatter_kernel<<<nbE, 256, 0, stream>>>(ei, rowptr, cursor, dis, csr, E);

  float* out0 = (float*)d_out;
  float* out1 = out0 + (size_t)N * NC;
  float* out2 = out1 + N;

  const float* cur = propA;
  float* nxt = propB;
  const int nbW = (N + 3) / 4;       // 4 waves (nodes) per 256-thread block
  for (int it = 0; it < NITER; ++it) {
    prop_step_kernel<<<nbW, 256, 0, stream>>>(cur, nxt, csr, rowptr, dis,
                                              halt_w, halt_b, steps, sumh,
                                              cont, xacc, N);
    const float* t = nxt; nxt = (float*)cur; cur = t;
  }
  final_kernel<<<nbW, 256, 0, stream>>>(xacc, steps, sumh, out0, out1, out2, N);
}

// Round 7
// 580.383 us; speedup vs baseline: 1.0220x; 1.0220x over previous
//
#include <hip/hip_runtime.h>
#include <hip/hip_bf16.h>

#define F_IN 512
#define NC 64      // HID == N_CLS == 64
#define NITER 10
#define BM 128     // MLP tile rows (391 blocks -> fills 256 CUs)

// ---------------------------------------------------------------------------
// Init per-node halting state.
__global__ __launch_bounds__(256) void init_state_kernel(
    float* __restrict__ steps, float* __restrict__ sumh, int* __restrict__ cont,
    int N) {
  int i = blockIdx.x * blockDim.x + threadIdx.x;
  if (i < N) { steps[i] = 1.0f; sumh[i] = 0.0f; cont[i] = 1; }
}

// ---------------------------------------------------------------------------
// Fused tiled MLP: out[r,:] = relu(x[r,:] @ W1 + b1) @ W2 + b2   (all fp32)
// 128 threads, tile 128x64, 8x8 per thread (16 FMA per ds_read_b128).
// xs layout: row-major [row][16 chunks], chunk kc stored at kc ^ ((row>>3)&7)
//   -> compute reads at fixed kc across 8 row-groups hit 8 distinct bank
//      quads (conflict-free); staging writes are dense b128.
// Accumulation order (k ascending) identical to previous rounds -> bitwise
// identical MLP output (halting decisions unchanged).
__global__ __launch_bounds__(128) void mlp_kernel(
    const float* __restrict__ x, const float* __restrict__ W1,
    const float* __restrict__ b1, const float* __restrict__ W2,
    const float* __restrict__ b2, float* __restrict__ out, int N) {
  __shared__ float xs[BM * NC];    // 32KB x k-tile / later h
  __shared__ float ws[NC * NC];    // 16KB W1 k-tile / later W2
  const int tid  = threadIdx.x;
  const int brow = blockIdx.x * BM;
  const int rg = tid >> 3;         // 0..15 row-group
  const int cg = tid & 7;          // 0..7 col-group
  const int r0 = rg * 8;
  const int c0 = cg * 8;
  const int keyr = rg & 7;

  float acc[8][8];
#pragma unroll
  for (int j = 0; j < 8; ++j) {
    float bv = b1[c0 + j];
#pragma unroll
    for (int i = 0; i < 8; ++i) acc[i][j] = bv;
  }

  for (int kt = 0; kt < F_IN; kt += 64) {
    // stage x k-tile: 128 rows x 64 k, row-major, chunk-XOR swizzled
#pragma unroll
    for (int q = 0; q < 16; ++q) {
      int c = q * 128 + tid;           // 2048 chunks
      int row = c >> 4, kc = c & 15;
      int gr = brow + row; if (gr >= N) gr = N - 1;
      float4 v = *reinterpret_cast<const float4*>(&x[(size_t)gr * F_IN + kt + kc * 4]);
      *reinterpret_cast<float4*>(&xs[row * NC + ((kc ^ ((row >> 3) & 7)) << 2)]) = v;
    }
    // stage W1 k-tile: rows kt..kt+63 are 16KB contiguous -> linear copy
#pragma unroll
    for (int q = 0; q < 8; ++q) {
      int c = q * 128 + tid;           // 1024 chunks
      *reinterpret_cast<float4*>(&ws[c * 4]) =
          *reinterpret_cast<const float4*>(&W1[(size_t)kt * NC + c * 4]);
    }
    __syncthreads();
#pragma unroll 4
    for (int kc = 0; kc < 16; ++kc) {
      float xv[8][4];
#pragma unroll
      for (int i = 0; i < 8; ++i) {
        float4 t = *reinterpret_cast<const float4*>(
            &xs[(r0 + i) * NC + ((kc ^ keyr) << 2)]);
        xv[i][0] = t.x; xv[i][1] = t.y; xv[i][2] = t.z; xv[i][3] = t.w;
      }
#pragma unroll
      for (int m = 0; m < 4; ++m) {
        float4 wa = *reinterpret_cast<const float4*>(&ws[(kc * 4 + m) * NC + c0]);
        float4 wb = *reinterpret_cast<const float4*>(&ws[(kc * 4 + m) * NC + c0 + 4]);
        float wr[8] = {wa.x, wa.y, wa.z, wa.w, wb.x, wb.y, wb.z, wb.w};
#pragma unroll
        for (int i = 0; i < 8; ++i)
#pragma unroll
          for (int j = 0; j < 8; ++j)
            acc[i][j] = fmaf(xv[i][m], wr[j], acc[i][j]);
      }
    }
    __syncthreads();
  }

  // ReLU; h -> xs (same swizzled layout, class dim = chunk dim)
#pragma unroll
  for (int i = 0; i < 8; ++i) {
    float4 ha = make_float4(fmaxf(acc[i][0], 0.f), fmaxf(acc[i][1], 0.f),
                            fmaxf(acc[i][2], 0.f), fmaxf(acc[i][3], 0.f));
    float4 hb = make_float4(fmaxf(acc[i][4], 0.f), fmaxf(acc[i][5], 0.f),
                            fmaxf(acc[i][6], 0.f), fmaxf(acc[i][7], 0.f));
    *reinterpret_cast<float4*>(&xs[(r0 + i) * NC + (((cg * 2 + 0) ^ keyr) << 2)]) = ha;
    *reinterpret_cast<float4*>(&xs[(r0 + i) * NC + (((cg * 2 + 1) ^ keyr) << 2)]) = hb;
  }
  // stage W2 (64x64 = 16KB, linear)
#pragma unroll
  for (int q = 0; q < 8; ++q) {
    int c = q * 128 + tid;
    *reinterpret_cast<float4*>(&ws[c * 4]) =
        *reinterpret_cast<const float4*>(&W2[c * 4]);
  }
  float acc2[8][8];
#pragma unroll
  for (int j = 0; j < 8; ++j) {
    float bv = b2[c0 + j];
#pragma unroll
    for (int i = 0; i < 8; ++i) acc2[i][j] = bv;
  }
  __syncthreads();
#pragma unroll 4
  for (int kc = 0; kc < 16; ++kc) {
    float xv[8][4];
#pragma unroll
    for (int i = 0; i < 8; ++i) {
      float4 t = *reinterpret_cast<const float4*>(
          &xs[(r0 + i) * NC + ((kc ^ keyr) << 2)]);
      xv[i][0] = t.x; xv[i][1] = t.y; xv[i][2] = t.z; xv[i][3] = t.w;
    }
#pragma unroll
    for (int m = 0; m < 4; ++m) {
      float4 wa = *reinterpret_cast<const float4*>(&ws[(kc * 4 + m) * NC + c0]);
      float4 wb = *reinterpret_cast<const float4*>(&ws[(kc * 4 + m) * NC + c0 + 4]);
      float wr[8] = {wa.x, wa.y, wa.z, wa.w, wb.x, wb.y, wb.z, wb.w};
#pragma unroll
      for (int i = 0; i < 8; ++i)
#pragma unroll
        for (int j = 0; j < 8; ++j)
          acc2[i][j] = fmaf(xv[i][m], wr[j], acc2[i][j]);
    }
  }
#pragma unroll
  for (int i = 0; i < 8; ++i) {
    int gr = brow + r0 + i;
    if (gr < N) {
      float4 oa = make_float4(acc2[i][0], acc2[i][1], acc2[i][2], acc2[i][3]);
      float4 ob = make_float4(acc2[i][4], acc2[i][5], acc2[i][6], acc2[i][7]);
      *reinterpret_cast<float4*>(&out[(size_t)gr * NC + c0]) = oa;
      *reinterpret_cast<float4*>(&out[(size_t)gr * NC + c0 + 4]) = ob;
    }
  }
}

// ---------------------------------------------------------------------------
// Degree histograms (int atomics -> deterministic counts).
__global__ __launch_bounds__(256) void hist_kernel(
    const int* __restrict__ ei, int* __restrict__ deg_i,
    int* __restrict__ indeg, int E) {
  int e = blockIdx.x * blockDim.x + threadIdx.x;
  if (e < E) {
    atomicAdd(&deg_i[ei[e]], 1);       // row = edge_index[0]
    atomicAdd(&indeg[ei[E + e]], 1);   // col = edge_index[1]
  }
}

// dis[i] = 1/sqrt(deg_i[i] + 1)
__global__ __launch_bounds__(256) void dis_kernel(
    const int* __restrict__ deg_i, float* __restrict__ dis, int N) {
  int i = blockIdx.x * blockDim.x + threadIdx.x;
  if (i < N) dis[i] = 1.0f / sqrtf((float)(deg_i[i] + 1));
}

// ---------------------------------------------------------------------------
// Exclusive scan of PADDED indeg (rounded up to multiple of 8) -> rowptr.
// Padded entries are zero-weight edges -> exact no-op in the gather, but
// make every edge list a whole number of 8-wide batches (no serial tail).
__device__ __forceinline__ int pad8(int v) { return (v + 7) & ~7; }

__global__ __launch_bounds__(256) void scan_sum_kernel(
    const int* __restrict__ indeg, int* __restrict__ bsum, int N) {
  __shared__ int sm[256];
  int tid = threadIdx.x;
  int i = blockIdx.x * 256 + tid;
  sm[tid] = (i < N) ? pad8(indeg[i]) : 0;
  __syncthreads();
  for (int s = 128; s > 0; s >>= 1) {
    if (tid < s) sm[tid] += sm[tid + s];
    __syncthreads();
  }
  if (tid == 0) bsum[blockIdx.x] = sm[0];
}

__global__ __launch_bounds__(256) void scan_bsum_kernel(int* __restrict__ bsum, int nb) {
  __shared__ int sm[256];
  int tid = threadIdx.x;
  int v = (tid < nb) ? bsum[tid] : 0;
  sm[tid] = v;
  __syncthreads();
  for (int s = 1; s < 256; s <<= 1) {
    int t = (tid >= s) ? sm[tid - s] : 0;
    __syncthreads();
    sm[tid] += t;
    __syncthreads();
  }
  if (tid < nb) bsum[tid] = sm[tid] - v;  // exclusive
}

__global__ __launch_bounds__(256) void scan_final_kernel(
    const int* __restrict__ indeg, const int* __restrict__ bsum,
    int* __restrict__ rowptr, int N) {
  __shared__ int sm[256];
  int tid = threadIdx.x;
  int i = blockIdx.x * 256 + tid;
  int v = (i < N) ? pad8(indeg[i]) : 0;
  sm[tid] = v;
  __syncthreads();
  for (int s = 1; s < 256; s <<= 1) {
    int t = (tid >= s) ? sm[tid - s] : 0;
    __syncthreads();
    sm[tid] += t;
    __syncthreads();
  }
  if (i < N) {
    rowptr[i] = bsum[blockIdx.x] + sm[tid] - v;
    if (i == N - 1) rowptr[N] = bsum[blockIdx.x] + sm[tid];  // padded total
  }
}

// ---------------------------------------------------------------------------
// Build destination-CSR entries: csr[pos] = {src, norm}. Pad slots keep the
// memset value {0, 0.0f} (zero-weight edge to node 0 -> exact no-op).
__global__ __launch_bounds__(256) void scatter_kernel(
    const int* __restrict__ ei, const int* __restrict__ rowptr,
    int* __restrict__ cursor, const float* __restrict__ dis,
    int2* __restrict__ csr, int E) {
  int e = blockIdx.x * blockDim.x + threadIdx.x;
  if (e < E) {
    int s = ei[e];
    int c = ei[E + e];
    int pos = rowptr[c] + atomicAdd(&cursor[c], 1);
    csr[pos] = make_int2(s, __float_as_int(dis[s] * dis[c]));
  }
}

// ---------------------------------------------------------------------------
// One adaptive-propagation step. One wave per node, lane = feature.
// Edge lists are padded to multiples of 8: uniform 8-deep batches only.
__global__ __launch_bounds__(256) void prop_step_kernel(
    const float* __restrict__ prop, float* __restrict__ prop_new,
    const int2* __restrict__ csr, const int* __restrict__ rowptr,
    const float* __restrict__ dis, const float* __restrict__ hw,
    const float* __restrict__ hb, float* __restrict__ steps,
    float* __restrict__ sumh, int* __restrict__ cont,
    float* __restrict__ xacc, int N) {
  int wid = (int)((blockIdx.x * blockDim.x + threadIdx.x) >> 6);
  if (wid >= N) return;
  int lane = threadIdx.x & 63;
  size_t rowoff = (size_t)wid * NC + lane;

  float oldv = prop[rowoff];
  float dc = dis[wid];
  int beg = __builtin_amdgcn_readfirstlane(rowptr[wid]);
  int end = __builtin_amdgcn_readfirstlane(rowptr[wid + 1]);

  float a[8];
  a[0] = dc * dc * oldv;   // self-loop: norm = dis[c]^2
#pragma unroll
  for (int u = 1; u < 8; ++u) a[u] = 0.0f;
  for (int i = beg; i < end; i += 8) {   // always full 8-batches
    int2 e[8];
#pragma unroll
    for (int u = 0; u < 8; ++u) e[u] = csr[i + u];
#pragma unroll
    for (int u = 0; u < 8; ++u)
      a[u] = fmaf(__int_as_float(e[u].y), prop[(size_t)e[u].x * NC + lane], a[u]);
  }
  float acc = ((a[0] + a[1]) + (a[2] + a[3])) + ((a[4] + a[5]) + (a[6] + a[7]));
  prop_new[rowoff] = acc;

  // hh = sigmoid(acc . halt_w + halt_b)
  float z = acc * hw[lane];
#pragma unroll
  for (int off = 32; off > 0; off >>= 1) z += __shfl_xor(z, off);
  z += hb[0];
  float hh = 1.0f / (1.0f + expf(-z));

  float st = steps[wid], sh = sumh[wid];
  int ct = cont[wid];
  bool prob = ((sh + hh) < 0.99f) && (ct != 0);
  float pf = prob ? 1.0f : 0.0f;
  st += pf;
  sh += pf * hh;
  bool cond = prob && (st < (float)NITER);
  float pp = cond ? sh : (1.0f - sh);
  float ctf = ct ? 1.0f : 0.0f;
  xacc[rowoff] += (acc * pp + oldv * (1.0f - pp)) * ctf;
  if (lane == 0) { steps[wid] = st; sumh[wid] = sh; cont[wid] = prob ? 1 : 0; }
}

// ---------------------------------------------------------------------------
// out0 = log_softmax(xacc/steps), out1 = steps, out2 = 1 - sum_h
__global__ __launch_bounds__(256) void final_kernel(
    const float* __restrict__ xacc, const float* __restrict__ steps,
    const float* __restrict__ sumh, float* __restrict__ out0,
    float* __restrict__ out1, float* __restrict__ out2, int N) {
  int wid = (int)((blockIdx.x * blockDim.x + threadIdx.x) >> 6);
  if (wid >= N) return;
  int lane = threadIdx.x & 63;
  float st = steps[wid];
  float v = xacc[(size_t)wid * NC + lane] / st;
  float m = v;
#pragma unroll
  for (int off = 32; off > 0; off >>= 1) m = fmaxf(m, __shfl_xor(m, off));
  float e = expf(v - m);
  float s = e;
#pragma unroll
  for (int off = 32; off > 0; off >>= 1) s += __shfl_xor(s, off);
  out0[(size_t)wid * NC + lane] = v - m - logf(s);
  if (lane == 0) { out1[wid] = st; out2[wid] = 1.0f - sumh[wid]; }
}

// ---------------------------------------------------------------------------
extern "C" void kernel_launch(void* const* d_in, const int* in_sizes, int n_in,
                              void* d_out, int out_size, void* d_ws, size_t ws_size,
                              hipStream_t stream) {
  const float* x      = (const float*)d_in[0];
  const int*   ei     = (const int*)d_in[1];
  const float* W1     = (const float*)d_in[2];
  const float* b1     = (const float*)d_in[3];
  const float* W2     = (const float*)d_in[4];
  const float* b2     = (const float*)d_in[5];
  const float* halt_w = (const float*)d_in[6];
  const float* halt_b = (const float*)d_in[7];

  const int N = in_sizes[0] / F_IN;   // 50000
  const int E = in_sizes[1] / 2;      // 800000
  const int EP = E + 8 * N;           // padded-CSR capacity

  // workspace carve-up (256B aligned)
  char* p = (char*)d_ws;
  auto alloc = [&](size_t bytes) {
    void* r = (void*)p;
    p += (bytes + 255) & ~(size_t)255;
    return r;
  };
  float* propA  = (float*)alloc((size_t)N * NC * 4);
  float* propB  = (float*)alloc((size_t)N * NC * 4);
  float* xacc   = (float*)alloc((size_t)N * NC * 4);
  int2*  csr    = (int2*)alloc((size_t)EP * 8);
  int*   rowptr = (int*)alloc((size_t)(N + 1) * 4);
  int*   deg_i  = (int*)alloc((size_t)N * 4);
  int*   indeg  = (int*)alloc((size_t)N * 4);
  int*   cursor = (int*)alloc((size_t)N * 4);
  float* dis    = (float*)alloc((size_t)N * 4);
  float* steps  = (float*)alloc((size_t)N * 4);
  float* sumh   = (float*)alloc((size_t)N * 4);
  int*   cont   = (int*)alloc((size_t)N * 4);
  int*   bsum   = (int*)alloc(1024);

  hipMemsetAsync(deg_i,  0, (size_t)N * 4, stream);
  hipMemsetAsync(indeg,  0, (size_t)N * 4, stream);
  hipMemsetAsync(cursor, 0, (size_t)N * 4, stream);
  hipMemsetAsync(xacc,   0, (size_t)N * NC * 4, stream);
  hipMemsetAsync(csr,    0, (size_t)EP * 8, stream);   // pads = {0, 0.0f}

  const int nbN = (N + 255) / 256;   // 196
  const int nbE = (E + 255) / 256;   // 3125
  const int nbM = (N + BM - 1) / BM; // 391

  init_state_kernel<<<nbN, 256, 0, stream>>>(steps, sumh, cont, N);
  mlp_kernel<<<nbM, 128, 0, stream>>>(x, W1, b1, W2, b2, propA, N);
  hist_kernel<<<nbE, 256, 0, stream>>>(ei, deg_i, indeg, E);
  dis_kernel<<<nbN, 256, 0, stream>>>(deg_i, dis, N);
  scan_sum_kernel<<<nbN, 256, 0, stream>>>(indeg, bsum, N);
  scan_bsum_kernel<<<1, 256, 0, stream>>>(bsum, nbN);
  scan_final_kernel<<<nbN, 256, 0, stream>>>(indeg, bsum, rowptr, N);
  scatter_kernel<<<nbE, 256, 0, stream>>>(ei, rowptr, cursor, dis, csr, E);

  float* out0 = (float*)d_out;
  float* out1 = out0 + (size_t)N * NC;
  float* out2 = out1 + N;

  const float* cur = propA;
  float* nxt = propB;
  const int nbW = (N + 3) / 4;       // 4 waves (nodes) per 256-thread block
  for (int it = 0; it < NITER; ++it) {
    prop_step_kernel<<<nbW, 256, 0, stream>>>(cur, nxt, csr, rowptr, dis,
                                              halt_w, halt_b, steps, sumh,
                                              cont, xacc, N);
    const float* t = nxt; nxt = (float*)cur; cur = t;
  }
  final_kernel<<<nbW, 256, 0, stream>>>(xacc, steps, sumh, out0, out1, out2, N);
}

// Round 9
// 554.537 us; speedup vs baseline: 1.0696x; 1.0466x over previous
//
#include <hip/hip_runtime.h>
#include <hip/hip_bf16.h>

#define F_IN 512
#define NC 64      // HID == N_CLS == 64
#define NITER 10
#define BM 128     // MLP tile rows (391 blocks)

typedef float fvec4 __attribute__((ext_vector_type(4)));  // clang-native vec

// ---------------------------------------------------------------------------
// Fused tiled MLP: out[r,:] = relu(x[r,:] @ W1 + b1) @ W2 + b2   (all fp32)
// 256 threads, tile 128x64, 8 rows x 4 cols per thread (10.7 FMA/ds_read_b128).
// xs layout: row-major [row][16 chunks of 4 floats], chunk kc stored at
// kc ^ ((row>>3)&7). Staging writes: each wave covers 4 full rows -> dense
// 1KB, conflict-free. Compute reads at fixed kc: 4 distinct rows (rg 0..3)
// hit 4 distinct bank-quads ((kc^rg)&7 injective), 16-lane broadcast each.
// Accumulation order (k ascending) identical to previous rounds -> bitwise
// identical MLP output (halting decisions unchanged).
__global__ __launch_bounds__(256) void mlp_kernel(
    const float* __restrict__ x, const float* __restrict__ W1,
    const float* __restrict__ b1, const float* __restrict__ W2,
    const float* __restrict__ b2, float* __restrict__ out, int N) {
  __shared__ float xs[BM * NC];    // 32KB x k-tile / later h
  __shared__ float ws[NC * NC];    // 16KB W1 k-tile / later W2
  const int tid  = threadIdx.x;
  const int brow = blockIdx.x * BM;
  const int rg = tid >> 4;         // 0..15 row-group (8 rows each)
  const int cg = tid & 15;         // 0..15 col-group (4 cols each)
  const int r0 = rg * 8;
  const int c0 = cg * 4;
  const int keyr = rg & 7;

  float acc[8][4];
#pragma unroll
  for (int j = 0; j < 4; ++j) {
    float bv = b1[c0 + j];
#pragma unroll
    for (int i = 0; i < 8; ++i) acc[i][j] = bv;
  }

  for (int kt = 0; kt < F_IN; kt += 64) {
    // stage x k-tile: 128 rows x 64 k, row-major, chunk-XOR swizzled
#pragma unroll
    for (int q = 0; q < 8; ++q) {
      int c = q * 256 + tid;           // 2048 chunks
      int row = c >> 4, kc = c & 15;
      int gr = brow + row; if (gr >= N) gr = N - 1;
      float4 v = *reinterpret_cast<const float4*>(&x[(size_t)gr * F_IN + kt + kc * 4]);
      *reinterpret_cast<float4*>(&xs[row * NC + ((kc ^ ((row >> 3) & 7)) << 2)]) = v;
    }
    // stage W1 k-tile (64x64 = 16KB contiguous)
#pragma unroll
    for (int q = 0; q < 4; ++q) {
      int c = q * 256 + tid;           // 1024 chunks
      *reinterpret_cast<float4*>(&ws[c * 4]) =
          *reinterpret_cast<const float4*>(&W1[(size_t)kt * NC + c * 4]);
    }
    __syncthreads();
#pragma unroll 4
    for (int kc = 0; kc < 16; ++kc) {
      float4 xq[8];
#pragma unroll
      for (int i = 0; i < 8; ++i)
        xq[i] = *reinterpret_cast<const float4*>(&xs[(r0 + i) * NC + ((kc ^ keyr) << 2)]);
#pragma unroll
      for (int m = 0; m < 4; ++m) {
        float4 wv = *reinterpret_cast<const float4*>(&ws[(kc * 4 + m) * NC + c0]);
        float wr[4] = {wv.x, wv.y, wv.z, wv.w};
#pragma unroll
        for (int i = 0; i < 8; ++i) {
          float xm = reinterpret_cast<const float*>(&xq[i])[m];
#pragma unroll
          for (int j = 0; j < 4; ++j) acc[i][j] = fmaf(xm, wr[j], acc[i][j]);
        }
      }
    }
    __syncthreads();
  }

  // ReLU; h -> xs (same swizzled layout; thread's 4 cols == chunk cg)
#pragma unroll
  for (int i = 0; i < 8; ++i) {
    float4 hv = make_float4(fmaxf(acc[i][0], 0.f), fmaxf(acc[i][1], 0.f),
                            fmaxf(acc[i][2], 0.f), fmaxf(acc[i][3], 0.f));
    *reinterpret_cast<float4*>(&xs[(r0 + i) * NC + ((cg ^ keyr) << 2)]) = hv;
  }
  // stage W2 (64x64, linear)
#pragma unroll
  for (int q = 0; q < 4; ++q) {
    int c = q * 256 + tid;
    *reinterpret_cast<float4*>(&ws[c * 4]) =
        *reinterpret_cast<const float4*>(&W2[c * 4]);
  }
  float acc2[8][4];
#pragma unroll
  for (int j = 0; j < 4; ++j) {
    float bv = b2[c0 + j];
#pragma unroll
    for (int i = 0; i < 8; ++i) acc2[i][j] = bv;
  }
  __syncthreads();
#pragma unroll 4
  for (int kc = 0; kc < 16; ++kc) {
    float4 xq[8];
#pragma unroll
    for (int i = 0; i < 8; ++i)
      xq[i] = *reinterpret_cast<const float4*>(&xs[(r0 + i) * NC + ((kc ^ keyr) << 2)]);
#pragma unroll
    for (int m = 0; m < 4; ++m) {
      float4 wv = *reinterpret_cast<const float4*>(&ws[(kc * 4 + m) * NC + c0]);
      float wr[4] = {wv.x, wv.y, wv.z, wv.w};
#pragma unroll
      for (int i = 0; i < 8; ++i) {
        float xm = reinterpret_cast<const float*>(&xq[i])[m];
#pragma unroll
        for (int j = 0; j < 4; ++j) acc2[i][j] = fmaf(xm, wr[j], acc2[i][j]);
      }
    }
  }
#pragma unroll
  for (int i = 0; i < 8; ++i) {
    int gr = brow + r0 + i;
    if (gr < N) {
      fvec4 o = {acc2[i][0], acc2[i][1], acc2[i][2], acc2[i][3]};
      __builtin_nontemporal_store(o, reinterpret_cast<fvec4*>(&out[(size_t)gr * NC + c0]));
    }
  }
}

// ---------------------------------------------------------------------------
// Degree histograms (int atomics -> deterministic counts).
__global__ __launch_bounds__(256) void hist_kernel(
    const int* __restrict__ ei, int* __restrict__ deg_i,
    int* __restrict__ indeg, int E) {
  int e = blockIdx.x * blockDim.x + threadIdx.x;
  if (e < E) {
    atomicAdd(&deg_i[ei[e]], 1);       // row = edge_index[0]
    atomicAdd(&indeg[ei[E + e]], 1);   // col = edge_index[1]
  }
}

// ---------------------------------------------------------------------------
// Exclusive scan of PADDED indeg (multiple of 8) -> rowptr; also dis[].
__device__ __forceinline__ int pad8(int v) { return (v + 7) & ~7; }

__global__ __launch_bounds__(256) void scan_sum_kernel(
    const int* __restrict__ indeg, int* __restrict__ bsum,
    const int* __restrict__ deg_i, float* __restrict__ dis, int N) {
  __shared__ int sm[256];
  int tid = threadIdx.x;
  int i = blockIdx.x * 256 + tid;
  sm[tid] = (i < N) ? pad8(indeg[i]) : 0;
  if (i < N) dis[i] = 1.0f / sqrtf((float)(deg_i[i] + 1));  // +1 self-loop
  __syncthreads();
  for (int s = 128; s > 0; s >>= 1) {
    if (tid < s) sm[tid] += sm[tid + s];
    __syncthreads();
  }
  if (tid == 0) bsum[blockIdx.x] = sm[0];
}

__global__ __launch_bounds__(256) void scan_bsum_kernel(int* __restrict__ bsum, int nb) {
  __shared__ int sm[256];
  int tid = threadIdx.x;
  int v = (tid < nb) ? bsum[tid] : 0;
  sm[tid] = v;
  __syncthreads();
  for (int s = 1; s < 256; s <<= 1) {
    int t = (tid >= s) ? sm[tid - s] : 0;
    __syncthreads();
    sm[tid] += t;
    __syncthreads();
  }
  if (tid < nb) bsum[tid] = sm[tid] - v;  // exclusive
}

__global__ __launch_bounds__(256) void scan_final_kernel(
    const int* __restrict__ indeg, const int* __restrict__ bsum,
    int* __restrict__ rowptr, int N) {
  __shared__ int sm[256];
  int tid = threadIdx.x;
  int i = blockIdx.x * 256 + tid;
  int v = (i < N) ? pad8(indeg[i]) : 0;
  sm[tid] = v;
  __syncthreads();
  for (int s = 1; s < 256; s <<= 1) {
    int t = (tid >= s) ? sm[tid - s] : 0;
    __syncthreads();
    sm[tid] += t;
    __syncthreads();
  }
  if (i < N) {
    rowptr[i] = bsum[blockIdx.x] + sm[tid] - v;
    if (i == N - 1) rowptr[N] = bsum[blockIdx.x] + sm[tid];  // padded total
  }
}

// ---------------------------------------------------------------------------
// Build destination-CSR entries: csr[pos] = {src, norm}.
__global__ __launch_bounds__(256) void scatter_kernel(
    const int* __restrict__ ei, const int* __restrict__ rowptr,
    int* __restrict__ cursor, const float* __restrict__ dis,
    int2* __restrict__ csr, int E) {
  int e = blockIdx.x * blockDim.x + threadIdx.x;
  if (e < E) {
    int s = ei[e];
    int c = ei[E + e];
    int pos = rowptr[c] + atomicAdd(&cursor[c], 1);
    csr[pos] = make_int2(s, __float_as_int(dis[s] * dis[c]));
  }
}

// Fill only the pad slots with {src=0, norm=0.0f} (exact no-op edges).
__global__ __launch_bounds__(256) void pad_fill_kernel(
    const int* __restrict__ rowptr, const int* __restrict__ indeg,
    int2* __restrict__ csr, int N) {
  int i = blockIdx.x * blockDim.x + threadIdx.x;
  if (i < N) {
    int e = rowptr[i] + indeg[i];
    int end = rowptr[i + 1];
    for (; e < end; ++e) csr[e] = make_int2(0, 0);
  }
}

// ---------------------------------------------------------------------------
// One adaptive-propagation step. One wave per node, lane = feature.
// Streams (csr, prop_new, xacc) use nontemporal hints so the hot gather
// buffer (prop, 12.8MB) keeps L2 residency. FIRST inlines the initial
// state; LAST fuses the final log_softmax epilogue and skips dead stores.
template<bool FIRST, bool LAST>
__global__ __launch_bounds__(256) void prop_step_kernel(
    const float* __restrict__ prop, float* __restrict__ prop_new,
    const int2* __restrict__ csr, const int* __restrict__ rowptr,
    const float* __restrict__ dis, const float* __restrict__ hw,
    const float* __restrict__ hb, float* __restrict__ steps,
    float* __restrict__ sumh, int* __restrict__ cont,
    float* __restrict__ xacc, float* __restrict__ out0,
    float* __restrict__ out1, float* __restrict__ out2, int N) {
  int wid = (int)((blockIdx.x * blockDim.x + threadIdx.x) >> 6);
  if (wid >= N) return;
  int lane = threadIdx.x & 63;
  size_t rowoff = (size_t)wid * NC + lane;

  float oldv = prop[rowoff];
  float dc = dis[wid];
  int beg = __builtin_amdgcn_readfirstlane(rowptr[wid]);
  int end = __builtin_amdgcn_readfirstlane(rowptr[wid + 1]);

  float a[8];
  a[0] = dc * dc * oldv;   // self-loop: norm = dis[c]^2
#pragma unroll
  for (int u = 1; u < 8; ++u) a[u] = 0.0f;
  for (int i = beg; i < end; i += 8) {   // padded: always full 8-batches
    long long raw[8];
#pragma unroll
    for (int u = 0; u < 8; ++u)
      raw[u] = __builtin_nontemporal_load(
          reinterpret_cast<const long long*>(csr + i + u));
#pragma unroll
    for (int u = 0; u < 8; ++u) {
      int src = (int)(raw[u] & 0xffffffffLL);
      float w = __int_as_float((int)(raw[u] >> 32));
      a[u] = fmaf(w, prop[(size_t)src * NC + lane], a[u]);
    }
  }
  float acc = ((a[0] + a[1]) + (a[2] + a[3])) + ((a[4] + a[5]) + (a[6] + a[7]));
  if (!LAST) __builtin_nontemporal_store(acc, &prop_new[rowoff]);

  // hh = sigmoid(acc . halt_w + halt_b)
  float z = acc * hw[lane];
#pragma unroll
  for (int off = 32; off > 0; off >>= 1) z += __shfl_xor(z, off);
  z += hb[0];
  float hh = 1.0f / (1.0f + expf(-z));

  float st, sh; int ct;
  if (FIRST) { st = 1.0f; sh = 0.0f; ct = 1; }
  else { st = steps[wid]; sh = sumh[wid]; ct = cont[wid]; }
  bool prob = ((sh + hh) < 0.99f) && (ct != 0);
  float pf = prob ? 1.0f : 0.0f;
  st += pf;
  sh += pf * hh;
  bool cond = prob && (st < (float)NITER);
  float pp = cond ? sh : (1.0f - sh);
  float ctf = ct ? 1.0f : 0.0f;
  float xa = FIRST ? 0.0f : __builtin_nontemporal_load(&xacc[rowoff]);
  float xnew = xa + (acc * pp + oldv * (1.0f - pp)) * ctf;

  if (!LAST) {
    __builtin_nontemporal_store(xnew, &xacc[rowoff]);
    if (lane == 0) { steps[wid] = st; sumh[wid] = sh; cont[wid] = prob ? 1 : 0; }
  } else {
    // fused final: out0 = log_softmax(xacc/steps), out1 = steps, out2 = 1-sumh
    float v = xnew / st;
    float m = v;
#pragma unroll
    for (int off = 32; off > 0; off >>= 1) m = fmaxf(m, __shfl_xor(m, off));
    float e = expf(v - m);
    float s = e;
#pragma unroll
    for (int off = 32; off > 0; off >>= 1) s += __shfl_xor(s, off);
    __builtin_nontemporal_store(v - m - logf(s), &out0[rowoff]);
    if (lane == 0) {
      __builtin_nontemporal_store(st, &out1[wid]);
      __builtin_nontemporal_store(1.0f - sh, &out2[wid]);
    }
  }
}

// ---------------------------------------------------------------------------
extern "C" void kernel_launch(void* const* d_in, const int* in_sizes, int n_in,
                              void* d_out, int out_size, void* d_ws, size_t ws_size,
                              hipStream_t stream) {
  const float* x      = (const float*)d_in[0];
  const int*   ei     = (const int*)d_in[1];
  const float* W1     = (const float*)d_in[2];
  const float* b1     = (const float*)d_in[3];
  const float* W2     = (const float*)d_in[4];
  const float* b2     = (const float*)d_in[5];
  const float* halt_w = (const float*)d_in[6];
  const float* halt_b = (const float*)d_in[7];

  const int N = in_sizes[0] / F_IN;   // 50000
  const int E = in_sizes[1] / 2;      // 800000
  const int EP = E + 8 * N;           // padded-CSR capacity

  // workspace carve-up (256B aligned)
  char* p = (char*)d_ws;
  auto alloc = [&](size_t bytes) {
    void* r = (void*)p;
    p += (bytes + 255) & ~(size_t)255;
    return r;
  };
  float* propA  = (float*)alloc((size_t)N * NC * 4);
  float* propB  = (float*)alloc((size_t)N * NC * 4);
  float* xacc   = (float*)alloc((size_t)N * NC * 4);
  int2*  csr    = (int2*)alloc((size_t)EP * 8);
  int*   rowptr = (int*)alloc((size_t)(N + 1) * 4);
  int*   deg_i  = (int*)alloc((size_t)N * 4);
  int*   indeg  = (int*)alloc((size_t)N * 4);
  int*   cursor = (int*)alloc((size_t)N * 4);
  float* dis    = (float*)alloc((size_t)N * 4);
  float* steps  = (float*)alloc((size_t)N * 4);
  float* sumh   = (float*)alloc((size_t)N * 4);
  int*   cont   = (int*)alloc((size_t)N * 4);
  int*   bsum   = (int*)alloc(1024);

  hipMemsetAsync(deg_i,  0, (size_t)N * 4, stream);
  hipMemsetAsync(indeg,  0, (size_t)N * 4, stream);
  hipMemsetAsync(cursor, 0, (size_t)N * 4, stream);

  const int nbN = (N + 255) / 256;   // 196
  const int nbE = (E + 255) / 256;   // 3125
  const int nbM = (N + BM - 1) / BM; // 391

  mlp_kernel<<<nbM, 256, 0, stream>>>(x, W1, b1, W2, b2, propA, N);
  hist_kernel<<<nbE, 256, 0, stream>>>(ei, deg_i, indeg, E);
  scan_sum_kernel<<<nbN, 256, 0, stream>>>(indeg, bsum, deg_i, dis, N);
  scan_bsum_kernel<<<1, 256, 0, stream>>>(bsum, nbN);
  scan_final_kernel<<<nbN, 256, 0, stream>>>(indeg, bsum, rowptr, N);
  scatter_kernel<<<nbE, 256, 0, stream>>>(ei, rowptr, cursor, dis, csr, E);
  pad_fill_kernel<<<nbN, 256, 0, stream>>>(rowptr, indeg, csr, N);

  float* out0 = (float*)d_out;
  float* out1 = out0 + (size_t)N * NC;
  float* out2 = out1 + N;

  const int nbW = (N + 3) / 4;       // 4 waves (nodes) per 256-thread block
  const float* cur = propA;
  float* nxt = propB;
  prop_step_kernel<true, false><<<nbW, 256, 0, stream>>>(
      cur, nxt, csr, rowptr, dis, halt_w, halt_b, steps, sumh, cont, xacc,
      out0, out1, out2, N);
  { const float* t = nxt; nxt = (float*)cur; cur = t; }
  for (int it = 1; it < NITER - 1; ++it) {
    prop_step_kernel<false, false><<<nbW, 256, 0, stream>>>(
        cur, nxt, csr, rowptr, dis, halt_w, halt_b, steps, sumh, cont, xacc,
        out0, out1, out2, N);
    const float* t = nxt; nxt = (float*)cur; cur = t;
  }
  prop_step_kernel<false, true><<<nbW, 256, 0, stream>>>(
      cur, nxt, csr, rowptr, dis, halt_w, halt_b, steps, sumh, cont, xacc,
      out0, out1, out2, N);
}